// Round 3
// baseline (208.141 us; speedup 1.0000x reference)
//
#include <hip/hip_runtime.h>

#define KNN_EPS 1e-8f
#define C_FEAT 128
#define M_QRY 262144
#define QPT 2   // queries per thread

typedef float f4 __attribute__((ext_vector_type(4)));  // native clang vector: OK for nontemporal builtins

__global__ __launch_bounds__(256) void knn_interp_kernel(
    const float* __restrict__ s_feats,
    const float* __restrict__ q_points,
    const float* __restrict__ s_points,
    const int*   __restrict__ nbr_idx,
    float* __restrict__ out)
{
    const int t  = blockIdx.x * blockDim.x + threadIdx.x;
    const int g  = t >> 5;            // 32-lane group id
    const int c4 = t & 31;            // float4 slot within the 128-ch row
    const int m0 = g * QPT;
    const int m1 = m0 + 1;

    // --- issue all index loads first (independent) ---
    const int a0 = nbr_idx[m0 * 3 + 0];
    const int a1 = nbr_idx[m0 * 3 + 1];
    const int a2 = nbr_idx[m0 * 3 + 2];
    const int b0 = nbr_idx[m1 * 3 + 0];
    const int b1 = nbr_idx[m1 * 3 + 1];
    const int b2 = nbr_idx[m1 * 3 + 2];

    // --- feature gathers depend only on indices: issue ASAP ---
    const f4 va0 = ((const f4*)(s_feats + (size_t)a0 * C_FEAT))[c4];
    const f4 va1 = ((const f4*)(s_feats + (size_t)a1 * C_FEAT))[c4];
    const f4 va2 = ((const f4*)(s_feats + (size_t)a2 * C_FEAT))[c4];
    const f4 vb0 = ((const f4*)(s_feats + (size_t)b0 * C_FEAT))[c4];
    const f4 vb1 = ((const f4*)(s_feats + (size_t)b1 * C_FEAT))[c4];
    const f4 vb2 = ((const f4*)(s_feats + (size_t)b2 * C_FEAT))[c4];

    // --- weight computation (broadcast loads, short chains) ---
    const float qax = q_points[m0 * 3 + 0];
    const float qay = q_points[m0 * 3 + 1];
    const float qaz = q_points[m0 * 3 + 2];
    const float qbx = q_points[m1 * 3 + 0];
    const float qby = q_points[m1 * 3 + 1];
    const float qbz = q_points[m1 * 3 + 2];

    float dx, dy, dz;

    dx = qax - s_points[a0 * 3 + 0];
    dy = qay - s_points[a0 * 3 + 1];
    dz = qaz - s_points[a0 * 3 + 2];
    float wa0 = __builtin_amdgcn_rcpf(dx * dx + dy * dy + dz * dz + KNN_EPS);
    dx = qax - s_points[a1 * 3 + 0];
    dy = qay - s_points[a1 * 3 + 1];
    dz = qaz - s_points[a1 * 3 + 2];
    float wa1 = __builtin_amdgcn_rcpf(dx * dx + dy * dy + dz * dz + KNN_EPS);
    dx = qax - s_points[a2 * 3 + 0];
    dy = qay - s_points[a2 * 3 + 1];
    dz = qaz - s_points[a2 * 3 + 2];
    float wa2 = __builtin_amdgcn_rcpf(dx * dx + dy * dy + dz * dz + KNN_EPS);

    dx = qbx - s_points[b0 * 3 + 0];
    dy = qby - s_points[b0 * 3 + 1];
    dz = qbz - s_points[b0 * 3 + 2];
    float wb0 = __builtin_amdgcn_rcpf(dx * dx + dy * dy + dz * dz + KNN_EPS);
    dx = qbx - s_points[b1 * 3 + 0];
    dy = qby - s_points[b1 * 3 + 1];
    dz = qbz - s_points[b1 * 3 + 2];
    float wb1 = __builtin_amdgcn_rcpf(dx * dx + dy * dy + dz * dz + KNN_EPS);
    dx = qbx - s_points[b2 * 3 + 0];
    dy = qby - s_points[b2 * 3 + 1];
    dz = qbz - s_points[b2 * 3 + 2];
    float wb2 = __builtin_amdgcn_rcpf(dx * dx + dy * dy + dz * dz + KNN_EPS);

    const float inv_a = __builtin_amdgcn_rcpf(wa0 + wa1 + wa2);
    const float inv_b = __builtin_amdgcn_rcpf(wb0 + wb1 + wb2);
    const float na0 = wa0 * inv_a, na1 = wa1 * inv_a, na2 = wa2 * inv_a;
    const float nb0 = wb0 * inv_b, nb1 = wb1 * inv_b, nb2 = wb2 * inv_b;

    const f4 ra = na0 * va0 + na1 * va1 + na2 * va2;
    const f4 rb = nb0 * vb0 + nb1 * vb1 + nb2 * vb2;

    // Non-temporal stores: output is write-once; keep it from evicting
    // s_feats out of L2.
    __builtin_nontemporal_store(ra, (f4*)(out + (size_t)m0 * C_FEAT) + c4);
    __builtin_nontemporal_store(rb, (f4*)(out + (size_t)m1 * C_FEAT) + c4);
}

extern "C" void kernel_launch(void* const* d_in, const int* in_sizes, int n_in,
                              void* d_out, int out_size, void* d_ws, size_t ws_size,
                              hipStream_t stream) {
    const float* s_feats  = (const float*)d_in[0];
    const float* q_points = (const float*)d_in[1];
    const float* s_points = (const float*)d_in[2];
    const int*   nbr_idx  = (const int*)d_in[3];
    float* out = (float*)d_out;

    const int total_threads = M_QRY * 32 / QPT;
    const int block = 256;
    const int grid  = (total_threads + block - 1) / block;  // 16384

    knn_interp_kernel<<<grid, block, 0, stream>>>(s_feats, q_points, s_points,
                                                  nbr_idx, out);
}